// Round 12
// baseline (299.529 us; speedup 1.0000x reference)
//
#include <hip/hip_runtime.h>
#include <hip/hip_bf16.h>
#include <math.h>

typedef __hip_bfloat16 bf16;
typedef __attribute__((ext_vector_type(8))) short s16x8;
typedef __attribute__((ext_vector_type(4))) short s16x4;
typedef __attribute__((ext_vector_type(4))) float fx4;
typedef __attribute__((ext_vector_type(2))) float f32x2;

#define Bv 2
#define Cv 96
#define Hv 128
#define Wv 128
#define Pv (Hv*Wv)          /* 16384 */
#define NPIX (Bv*Pv)        /* 32768 */
#define Gv 12
#define Kv 9
#define PPB 7               /* pixels per dka block */
#define NPT 64              /* 63 points + 1 pad    */
#define SROW 104            /* dka s_s row pitch (shorts) — 208B, 16B-aligned rows */
#define KROW 200            /* dka kv_s row pitch (shorts) — 400B, 16B-aligned rows */

__device__ __forceinline__ float b2f(bf16 x) { return __bfloat162float(x); }
__device__ __forceinline__ bf16 f2b(float x) { return __float2bfloat16(x); }

// async 16B global -> LDS (DMA, no VGPR round-trip). LDS dest is wave-uniform
// base + lane*16 (linear); per-lane GLOBAL address may be arbitrary.
__device__ __forceinline__ void gld16(const void* g, void* l) {
    __builtin_amdgcn_global_load_lds(
        (const __attribute__((address_space(1))) unsigned int*)g,
        (__attribute__((address_space(3))) unsigned int*)l, 16, 0, 0);
}

// dual-dtype input load: isf=1 -> float32, isf=0 -> bf16
__device__ __forceinline__ float ldin(const void* p, size_t i, int isf) {
    return isf ? ((const float*)p)[i] : __bfloat162float(((const bf16*)p)[i]);
}

// packed bilinear accumulate: acc[4] (8 ch as f32 pairs) += wt * bf16x8(d)
__device__ __forceinline__ void acc_pk(f32x2 acc[4], uint4 d, float wt) {
    f32x2 w2; w2.x = wt; w2.y = wt;
    #pragma unroll
    for (int q = 0; q < 4; q++) {
        unsigned u = (&d.x)[q];
        f32x2 v;
        v.x = __uint_as_float(u << 16);
        v.y = __uint_as_float(u & 0xffff0000u);
        acc[q] += w2 * v;
    }
}

__device__ __forceinline__ s16x8 pack8(const f32x2 a[4]) {
    s16x8 st;
    #pragma unroll
    for (int q = 0; q < 4; q++) {
        bf16 l = f2b(a[q].x), h = f2b(a[q].y);
        st[q*2]   = *(short*)&l;
        st[q*2+1] = *(short*)&h;
    }
    return st;
}

// ---------------------------------------------------------------------------
// dtype detection (f32 read as bf16 shows NaN/Inf bit patterns in low halves)
// + zero-fill of the zbuf region (OOB source for global_load_lds staging).
// ---------------------------------------------------------------------------
__global__ void detect_dtype(const unsigned short* __restrict__ x, int* __restrict__ flag,
                             float* __restrict__ zbuf)
{
    __shared__ int bad;
    if (threadIdx.x == 0) bad = 0;
    if (threadIdx.x < 64) zbuf[threadIdx.x] = 0.f;   // 256B zero region
    __syncthreads();
    int cnt = 0;
    for (int i = threadIdx.x; i < 32768; i += 256) {
        unsigned short u = x[i];
        if ((u & 0x7F80) == 0x7F80) cnt++;
    }
    atomicAdd(&bad, cnt);
    __syncthreads();
    if (threadIdx.x == 0) flag[0] = (bad > 0) ? 1 : 0;   // 1 = float32 inputs
}

// ---------------------------------------------------------------------------
// transpose_feats: [b][c][p] -> px-major bf16 via LDS tile.
// Phase A: coalesced read along p (lane=pixel), store LDS [px][c] (pitch 104).
// Phase B: contiguous s16x8 bursts to cat[gp][0..95] and fkvclb[gp][0..95].
// ---------------------------------------------------------------------------
__global__ void transpose_feats(const int* __restrict__ flag,
                                const void* ft, const void* fkv,
                                bf16* __restrict__ cat, bf16* __restrict__ fkvclb)
{
    __shared__ short tft[64*104];
    __shared__ short tkv[64*104];
    int tid = threadIdx.x;
    int isf = flag[0];
    int gp0 = blockIdx.x * 64;           // 64 | Pv -> whole tile in one batch b
    int bb  = gp0 >> 14;
    int p0  = gp0 & (Pv-1);

    // phase A: 96 c x 64 px; lane = px (coalesced); 24 iters per tensor
    for (int e = tid; e < 96*64; e += 256) {
        int c = e >> 6, dp = e & 63;
        size_t gi = ((size_t)bb*96 + c)*Pv + p0 + dp;
        bf16 v1 = f2b(ldin(ft,  gi, isf));
        bf16 v2 = f2b(ldin(fkv, gi, isf));
        tft[dp*104 + c] = *(short*)&v1;
        tkv[dp*104 + c] = *(short*)&v2;
    }
    __syncthreads();

    // phase B: 64 px x 12 groups; consecutive lanes cover one pixel's 192B
    for (int u = tid; u < 64*12; u += 256) {
        int g = u % 12, px = u / 12;
        s16x8 a = *(const s16x8*)&tft[px*104 + g*8];
        s16x8 b = *(const s16x8*)&tkv[px*104 + g*8];
        *(s16x8*)(cat    + (size_t)(gp0+px)*224 + g*8) = a;
        *(s16x8*)(fkvclb + (size_t)(gp0+px)*96  + g*8) = b;
    }
}

// ---------------------------------------------------------------------------
// prep_weights: build MFMA A-layout weight buffers (bf16) + flowf + biases.
// wA3 in 224-co layout (216 real + 8 pad) for conv3's COF=2/GY=7 retile.
// ---------------------------------------------------------------------------
__global__ void prep_weights(const int* __restrict__ flag,
    const void* flow,
    const void* cw1, const void* cb1, const void* a1,
    const void* cw2, const void* cb2, const void* a2,
    const void* cw3, const void* cb3,
    const void* wq, const void* bq, const void* wk, const void* bk,
    const void* wv, const void* bv, const void* wo, const void* bo,
    const void* wm1, const void* bm1, const void* wm2, const void* bm2,
    float* __restrict__ flowf,
    bf16* __restrict__ wAq, bf16* __restrict__ wAo, bf16* __restrict__ wAkv,
    bf16* __restrict__ wA1, bf16* __restrict__ wA2, bf16* __restrict__ wA3,
    bf16* __restrict__ wAm1, bf16* __restrict__ wAm2,
    float* __restrict__ biasf)
{
    int isf = flag[0];
    size_t i = (size_t)blockIdx.x * 256 + threadIdx.x;
    if (i < (size_t)Bv*2*Pv) flowf[i] = ldin(flow, i, isf);

    // conv1 weights: [192][194][9] -> wA1[t<9][kc<7][co<192][32]
    if (i < 9*7*192*32) {
        int q = (int)(i & 31);
        int rest = (int)(i >> 5);
        int co = rest % 192; rest /= 192;
        int kc = rest % 7;   int t = rest / 7;
        int ci = kc*32 + q;
        float v = (ci < 194) ? ldin(cw1, (size_t)co*194*9 + (size_t)ci*9 + t, isf) : 0.f;
        wA1[i] = f2b(v);
    }
    // conv2: [96][192][9] -> wA2[t<9][kc<6][co<96][32]
    if (i < 9*6*96*32) {
        int q = (int)(i & 31);
        int rest = (int)(i >> 5);
        int co = rest % 96; rest /= 96;
        int kc = rest % 6;  int t = rest / 6;
        int ci = kc*32 + q;
        wA2[i] = f2b(ldin(cw2, (size_t)co*192*9 + (size_t)ci*9 + t, isf));
    }
    // conv3: [216][96][9] -> wA3[t<9][kc<3][co<224][32], co>=216 zero
    if (i < 9*3*224*32) {
        int q = (int)(i & 31);
        int rest = (int)(i >> 5);
        int co = rest % 224; rest /= 224;
        int kc = rest % 3;   int t = rest / 3;
        int ci = kc*32 + q;
        float v = (co < 216) ? ldin(cw3, (size_t)co*96*9 + (size_t)ci*9 + t, isf) : 0.f;
        wA3[i] = f2b(v);
    }
    // mlp1: [192][96] -> wAm1[kc<3][co<192][32]
    if (i < 3*192*32) {
        int q = (int)(i & 31);
        int rest = (int)(i >> 5);
        int co = rest % 192;
        int kc = rest / 192;
        wAm1[i] = f2b(ldin(wm1, (size_t)co*96 + kc*32 + q, isf));
    }
    // mlp2: [96][192] -> wAm2[kc<6][co<96][32]
    if (i < 6*96*32) {
        int q = (int)(i & 31);
        int rest = (int)(i >> 5);
        int co = rest % 96;
        int kc = rest / 96;
        wAm2[i] = f2b(ldin(wm2, (size_t)co*192 + kc*32 + q, isf));
    }
    // wq / wo: [96][96] -> A-layout [kc<3][co<96][32]
    if (i < 3*96*32) {
        int q = (int)(i & 31);
        int rest = (int)(i >> 5);
        int co = rest % 96;
        int kc = rest / 96;
        wAq[i] = f2b(ldin(wq, (size_t)co*96 + kc*32 + q, isf));
        wAo[i] = f2b(ldin(wo, (size_t)co*96 + kc*32 + q, isf));
    }
    // wk/wv fused A-layout: wAkv[kc<3][co<192][32]; co<96 -> wk[co], co>=96 -> wv[co-96]
    if (i < 3*192*32) {
        int q = (int)(i & 31);
        int rest = (int)(i >> 5);
        int co = rest % 192;
        int kc = rest / 192;
        int ci = kc*32 + q;
        float v = (co < 96) ? ldin(wk, (size_t)co*96 + ci, isf)
                            : ldin(wv, (size_t)(co-96)*96 + ci, isf);
        wAkv[i] = f2b(v);
    }
    if (i < 192) biasf[i]       = ldin(cb1, i, isf);
    if (i < 192) biasf[192+i]   = ldin(a1, i, isf);
    if (i < 96)  biasf[384+i]   = ldin(cb2, i, isf);
    if (i < 96)  biasf[480+i]   = ldin(a2, i, isf);
    if (i < 216) biasf[576+i]   = ldin(cb3, i, isf);
    if (i < 96) {
        biasf[792+i]  = ldin(bq, i, isf);
        biasf[888+i]  = ldin(bk, i, isf);
        biasf[984+i]  = ldin(bv, i, isf);
        biasf[1080+i] = ldin(bo, i, isf);
        biasf[1368+i] = ldin(bm2, i, isf);
    }
    if (i < 192) biasf[1176+i] = ldin(bm1, i, isf);
}

// ---------------------------------------------------------------------------
// cat groups 12..27 only (feat_t groups 0..11 written by transpose_feats).
// 12..23 = flow-warped kv (packed bilinear), 24 = flow+pad, 25..27 = 0.
// ---------------------------------------------------------------------------
__global__ void build_cat(const bf16* __restrict__ fkvclb,
                          const float* __restrict__ flowf, bf16* __restrict__ cat)
{
    int idx = blockIdx.x * 256 + threadIdx.x;
    if (idx >= NPIX*16) return;
    int grp = 12 + (idx & 15);
    int gp  = idx >> 4;
    int p   = gp & (Pv-1);
    int bb  = gp >> 14;
    s16x8 st;
    if (grp < 24) {
        int g = grp - 12;
        int py = p >> 7, px = p & (Wv-1);
        float xs = (float)px + flowf[((size_t)bb*2 + 0)*Pv + p];
        float ys = (float)py + flowf[((size_t)bb*2 + 1)*Pv + p];
        float x0f = floorf(xs), y0f = floorf(ys);
        float wx = xs - x0f, wy = ys - y0f;
        int x0 = (int)x0f, y0 = (int)y0f;
        const bf16* base = fkvclb + ((size_t)bb*Pv)*96 + g*8;
        float w[4]; uint4 t4[4];
        #pragma unroll
        for (int t = 0; t < 4; t++) {
            int xi = x0 + (t & 1), yi = y0 + (t >> 1);
            float wt = ((t & 1) ? wx : 1.f - wx) * ((t >> 1) ? wy : 1.f - wy);
            bool vld = (xi >= 0) & (xi < Wv) & (yi >= 0) & (yi < Hv);
            int xc = min(max(xi, 0), Wv-1), yc = min(max(yi, 0), Hv-1);
            w[t] = vld ? wt : 0.f;
            t4[t] = *(const uint4*)(base + (size_t)(yc*Wv + xc)*96);
        }
        f32x2 acc[4];
        #pragma unroll
        for (int q = 0; q < 4; q++) { acc[q].x = 0.f; acc[q].y = 0.f; }
        #pragma unroll
        for (int t = 0; t < 4; t++) acc_pk(acc, t4[t], w[t]);
        st = pack8(acc);
    } else if (grp == 24) {
        float fx = flowf[((size_t)bb*2 + 0)*Pv + p];
        float fy = flowf[((size_t)bb*2 + 1)*Pv + p];
        bf16 b0 = f2b(fx), b1 = f2b(fy);
        st[0] = *(short*)&b0; st[1] = *(short*)&b1;
        #pragma unroll
        for (int j = 2; j < 8; j++) st[j] = 0;
    } else {
        #pragma unroll
        for (int j = 0; j < 8; j++) st[j] = 0;
    }
    *(s16x8*)(cat + (size_t)gp*224 + grp*8) = st;
}

// ---------------------------------------------------------------------------
// MFMA implicit-GEMM conv/1x1. 1-D grid of 128*GY*Bv blocks, XCD-aware decode.
// Staging via __builtin_amdgcn_global_load_lds (16B DMA, no VGPR round-trip,
// no spill possible). LDS is LINEAR in chunk index; bank-conflict swizzle is
// applied on the SOURCE address (rule #21): LDS chunk (row,kqs) holds global
// chunk (row, kqs ^ ((row>>1)&3)); readers XOR the same key.
// OOB border pixels: source redirected to a 256B zero buffer (zbuf).
// MODE 0: PReLU -> bf16 px-major    MODE 1: plain -> bf16 px-major (guard co<216)
// ---------------------------------------------------------------------------
template<int CSTR, int CIN_PAD, int COTOT, int COF, int TAPS, int MODE, int OCS, int GY>
__launch_bounds__(256)
__global__ void conv_mfma(const bf16* __restrict__ in, const bf16* __restrict__ wA,
                          const float* __restrict__ bias, const float* __restrict__ alpha,
                          const float* __restrict__ zbuf, const int* __restrict__ flag,
                          void* __restrict__ outp, void* __restrict__ out2)
{
    constexpr int NC = CIN_PAD / 32;
    constexpr int LDS_PX = (TAPS == 9) ? 3*130 : 128;
    constexpr int NITEMS = LDS_PX * 4;              // input 16B chunks per kc
    constexpr int NSTG = (NITEMS + 255) / 256;
    constexpr int NWCH  = TAPS * COF * 64;          // weight 16B chunks per kc
    constexpr int NWSTG = (NWCH + 255) / 256;
    __shared__ __align__(16) short sbuf[LDS_PX * 32];        // linear chunks
    __shared__ __align__(16) short wlds[TAPS * COF * 512];   // linear chunks

    int tid = threadIdx.x;
    int wave = tid >> 6, lane = tid & 63;
    int n = lane & 15, kq = lane >> 4;

    int bid = blockIdx.x;
    int xcd = bid & 7, idx = bid >> 3;
    int y   = xcd * 16 + (idx & 15);
    int cob = ((idx >> 4) % GY) * (COF*16);
    int bb  = idx / (16*GY);

    // async input staging: chunk i -> sbuf linear; source pre-swizzled
    auto stage_in = [&](int kc) {
        #pragma unroll
        for (int s = 0; s < NSTG; s++) {
            int i = s*256 + tid;
            if (i < NITEMS) {
                int pxr = i >> 2;
                int kqs = i & 3;
                int part = kqs ^ ((pxr >> 1) & 3);
                const bf16* ap;
                if (TAPS == 9) {
                    int r = pxr / 130; int px = pxr - r*130;
                    int yy = y + r - 1, xx = px - 1;
                    bool inb = (yy >= 0) & (yy < Hv) & (xx >= 0) & (xx < Wv);
                    ap = inb ? (in + ((size_t)(bb*Pv + yy*Wv + xx)*CSTR + kc*32 + part*8))
                             : (const bf16*)zbuf;
                } else {
                    ap = in + ((size_t)(bb*Pv + y*Wv + pxr)*CSTR + kc*32 + part*8);
                }
                gld16(ap, &sbuf[(size_t)(i & ~63) * 8]);   // wave-uniform base
            }
        }
    };
    // async weight staging: chunk i -> wlds linear; source pre-swizzled
    auto stage_w = [&](int kc) {
        #pragma unroll
        for (int s = 0; s < NWSTG; s++) {
            int i = s*256 + tid;
            if (i < NWCH) {
                int t = i / (COF*64);
                int rem = i - t*(COF*64);
                int row = rem >> 2, kqs = rem & 3;
                int part = kqs ^ ((row >> 1) & 3);
                const bf16* ap = wA + ((size_t)((t*NC + kc)*COTOT + cob + row))*32 + part*8;
                gld16(ap, &wlds[(size_t)(i & ~63) * 8]);   // wave-uniform base
            }
        }
    };

    fx4 acc[COF][2];
    #pragma unroll
    for (int f = 0; f < COF; f++)
        #pragma unroll
        for (int j = 0; j < 2; j++)
            acc[f][j] = (fx4){0.f, 0.f, 0.f, 0.f};

    int kqsw = kq ^ ((n >> 1) & 3);                  // weight-read swizzled chunk

    for (int kc = 0; kc < NC; kc++) {
        stage_in(kc); stage_w(kc);
        __syncthreads();                             // drains vmcnt (LDS ready)
        #pragma unroll
        for (int t = 0; t < TAPS; t++) {
            s16x8 wf[COF];
            #pragma unroll
            for (int f = 0; f < COF; f++)
                wf[f] = *(const s16x8*)&wlds[(size_t)(((t*COF + f)*16 + n)*4 + kqsw) * 8];
            #pragma unroll
            for (int j = 0; j < 2; j++) {
                int pxs;
                if (TAPS == 9) {
                    int r = t / 3, dx = t % 3;
                    pxs = r*130 + wave*32 + j*16 + n + dx;
                } else {
                    pxs = wave*32 + j*16 + n;
                }
                int kqi = kq ^ ((pxs >> 1) & 3);
                s16x8 bfr = *(const s16x8*)&sbuf[(size_t)(pxs*4 + kqi) * 8];
                #pragma unroll
                for (int f = 0; f < COF; f++)
                    acc[f][j] = __builtin_amdgcn_mfma_f32_16x16x32_bf16(wf[f], bfr, acc[f][j], 0, 0, 0);
            }
        }
        __syncthreads();                             // WAR before next staging
    }

    // epilogue: D col=lane&15 (pixel), row=(lane>>4)*4+reg (co)
    int pxbase = wave*32;
    #pragma unroll
    for (int f = 0; f < COF; f++) {
        int co0 = cob + f*16 + kq*4;
        if (MODE == 1 && co0 >= 216) continue;
        #pragma unroll
        for (int j = 0; j < 2; j++) {
            int px = pxbase + j*16 + n;
            size_t gp = (size_t)bb*Pv + (size_t)y*Wv + px;
            fx4 fr = acc[f][j];
            s16x4 st;
            #pragma unroll
            for (int rg = 0; rg < 4; rg++) {
                float v = fr[rg] + bias[co0 + rg];
                if (MODE == 0) { float a = alpha[co0 + rg]; v = (v >= 0.f) ? v : a*v; }
                bf16 bvv = f2b(v);
                st[rg] = *(short*)&bvv;
            }
            *(s16x4*)((bf16*)outp + gp*OCS + co0) = st;
        }
    }
    (void)flag; (void)out2;
}

// ---------------------------------------------------------------------------
// Fused deformable attention: sample -> kv MFMA GEMM -> softmax -> o.
// Block 256 = 4 waves, 7 pixels = 63 points (+1 pad) per block.
// Phase-1 mapping: tid -> (pt = tid>>2, g = (tid&3)*3 + r); r-invariant pixel
// decode; 2-stage gather pipeline. kv_s ALIASES s_s.
// Phase 4: one thread per (pixel, head) — head dim 8 is contiguous in kv_s
// rows and q_bf, so q/k/v are single 16B vectors. No shfl, no scalar reads.
// ---------------------------------------------------------------------------
__launch_bounds__(256, 4)
__global__ void dka_kernel(const float* __restrict__ flowf, const bf16* __restrict__ fkvclb,
    const bf16* __restrict__ off3, const bf16* __restrict__ q_bf,
    const bf16* __restrict__ wAkv, const float* __restrict__ bkf, const float* __restrict__ bvf,
    bf16* __restrict__ o_bf)
{
    __shared__ short smem[NPT*KROW];    // union: s_s [pt][SROW] then kv_s [pt][KROW]
    short* s_s  = smem;
    short* kv_s = smem;

    int tid = threadIdx.x;
    int pb0 = blockIdx.x * PPB;

    // --- phase 1 prologue (r-invariant) ---
    int pt  = tid >> 2;                 // point 0..63
    int gb  = (tid & 3) * 3;            // group base {0,3,6,9}
    int pxl = pt / 9;
    int tap = pt - pxl*9;
    int gp0 = pb0 + pxl;
    bool act = (pt < 63) && (gp0 < NPIX);
    int gp = act ? gp0 : (NPIX-1);
    int bb = gp >> 14, p = gp & (Pv-1);
    int py = p >> 7, px = p & (Wv-1);
    float fx = flowf[((size_t)bb*2 + 0)*Pv + p];
    float fy = flowf[((size_t)bb*2 + 1)*Pv + p];
    float sbx = (float)(px + (tap % 3) - 1) + fx;
    float sby = (float)(py + (tap / 3) - 1) + fy;
    const bf16* kvbase = fkvclb + ((size_t)bb*Pv)*96;
    unsigned owv[3];
    #pragma unroll
    for (int r = 0; r < 3; r++)
        owv[r] = *(const unsigned*)(off3 + (size_t)gp*216 + ((gb + r)*9 + tap)*2);  // (dy,dx)

    float wst[2][4]; uint4 tst[2][4];
    auto stage = [&](int r, int s) {
        unsigned ow = owv[r];
        unsigned short lo16 = (unsigned short)(ow & 0xFFFFu);
        unsigned short hi16 = (unsigned short)(ow >> 16);
        float sy = sby + b2f(*(bf16*)&lo16);
        float sx = sbx + b2f(*(bf16*)&hi16);
        float x0f = floorf(sx), y0f = floorf(sy);
        float wx1 = sx - x0f, wy1 = sy - y0f;
        float wx0 = 1.f - wx1, wy0 = 1.f - wy1;
        int ix0 = (int)x0f, iy0 = (int)y0f;
        bool vx0 = (unsigned)ix0     < (unsigned)Wv;
        bool vx1 = (unsigned)(ix0+1) < (unsigned)Wv;
        bool vy0 = (unsigned)iy0     < (unsigned)Hv;
        bool vy1 = (unsigned)(iy0+1) < (unsigned)Hv;
        float mx0 = (act && vx0) ? wx0 : 0.f;
        float mx1 = (act && vx1) ? wx1 : 0.f;
        float my0 = vy0 ? wy0 : 0.f;
        float my1 = vy1 ? wy1 : 0.f;
        wst[s][0] = mx0*my0; wst[s][1] = mx1*my0;
        wst[s][2] = mx0*my1; wst[s][3] = mx1*my1;
        int xc0 = min(max(ix0,   0), Wv-1), xc1 = min(max(ix0+1, 0), Wv-1);
        int yc0 = min(max(iy0,   0), Hv-1), yc1 = min(max(iy0+1, 0), Hv-1);
        const bf16* bg = kvbase + (gb + r)*8;
        int r0 = yc0*(Wv*96), r1 = yc1*(Wv*96);
        int c0 = xc0*96,      c1 = xc1*96;
        tst[s][0] = *(const uint4*)(bg + r0 + c0);
        tst[s][1] = *(const uint4*)(bg + r0 + c1);
        tst[s][2] = *(const uint4*)(bg + r1 + c0);
        tst[s][3] = *(const uint4*)(bg + r1 + c1);
    };
    auto emit = [&](int r, int s) {
        f32x2 acc[4];
        #pragma unroll
        for (int q = 0; q < 4; q++) { acc[q].x = 0.f; acc[q].y = 0.f; }
        #pragma unroll
        for (int t = 0; t < 4; t++) acc_pk(acc, tst[s][t], wst[s][t]);
        s16x8 st = pack8(acc);
        *(s16x8*)&s_s[pt*SROW + (gb + r)*8] = st;
    };

    stage(0, 0);
    asm volatile("" ::: "memory");   // force r=0 gathers issued
    stage(1, 1);
    asm volatile("" ::: "memory");   // force r=1 gathers issued before consuming r=0
    emit(0, 0);
    stage(2, 0);
    asm volatile("" ::: "memory");
    emit(1, 1);
    emit(2, 0);
    __syncthreads();

    // --- phase 2: kv = wAkv @ s  (M=192 split over waves, N=64, K=96) ---
    {
        int wave = tid >> 6, lane = tid & 63;
        int n = lane & 15, kq = lane >> 4;
        fx4 acc[3][4];
        #pragma unroll
        for (int mi = 0; mi < 3; mi++)
            #pragma unroll
            for (int nf = 0; nf < 4; nf++)
                acc[mi][nf] = (fx4){0.f, 0.f, 0.f, 0.f};
        #pragma unroll
        for (int kc = 0; kc < 3; kc++) {
            s16x8 b[4];
            #pragma unroll
            for (int nf = 0; nf < 4; nf++)
                b[nf] = *(const s16x8*)&s_s[(nf*16 + n)*SROW + kc*32 + kq*8];
            #pragma unroll
            for (int mi = 0; mi < 3; mi++) {
                s16x8 a = *(const s16x8*)(wAkv + ((size_t)(kc*192 + (wave*3 + mi)*16 + n))*32 + kq*8);
                #pragma unroll
                for (int nf = 0; nf < 4; nf++)
                    acc[mi][nf] = __builtin_amdgcn_mfma_f32_16x16x32_bf16(a, b[nf], acc[mi][nf], 0, 0, 0);
            }
        }
        __syncthreads();   // all s_s reads drained; kv_s may now overwrite the region
        // phase 3: stage kv to LDS. D: col=point(lane&15), row=co((lane>>4)*4+rg)
        #pragma unroll
        for (int mi = 0; mi < 3; mi++)
            #pragma unroll
            for (int nf = 0; nf < 4; nf++) {
                s16x4 st;
                #pragma unroll
                for (int rg = 0; rg < 4; rg++) {
                    bf16 bv = f2b(acc[mi][nf][rg]);
                    st[rg] = *(short*)&bv;
                }
                *(s16x4*)&kv_s[(size_t)(nf*16 + n)*KROW + (wave*3 + mi)*16 + kq*4] = st;
            }
    }
    __syncthreads();

    // --- phase 4: per-(pixel,head) lane-local softmax (no shfl, no u16 reads).
    // bk hoisted: qb = sum_d q_d*bk_d; bv hoisted: sum_k p_k = 1.
    {
        int u = tid;                       // unit = pixel*12 + head, 84 units
        int pxl4 = u / 12, h = u - pxl4*12;
        int gp4 = pb0 + pxl4;
        if (u < PPB*12 && gp4 < NPIX) {
            uint4 q8 = *(const uint4*)(q_bf + (size_t)gp4*96 + h*8);
            f32x2 q2[4];
            #pragma unroll
            for (int j = 0; j < 4; j++) {
                unsigned uu = (&q8.x)[j];
                q2[j].x = __uint_as_float(uu << 16);
                q2[j].y = __uint_as_float(uu & 0xffff0000u);
            }
            const f32x2* bk2 = (const f32x2*)(bkf + h*8);
            const f32x2* bv2 = (const f32x2*)(bvf + h*8);
            f32x2 qb2; qb2.x = 0.f; qb2.y = 0.f;
            #pragma unroll
            for (int j = 0; j < 4; j++) qb2 += q2[j] * bk2[j];
            float qb = qb2.x + qb2.y;
            float lg[9];
            #pragma unroll
            for (int k = 0; k < 9; k++) {
                uint4 k8 = *(const uint4*)&kv_s[(pxl4*9 + k)*KROW + h*8];
                f32x2 s2; s2.x = 0.f; s2.y = 0.f;
                #pragma unroll
                for (int j = 0; j < 4; j++) {
                    unsigned uu = (&k8.x)[j];
                    f32x2 kv2;
                    kv2.x = __uint_as_float(uu << 16);
                    kv2.y = __uint_as_float(uu & 0xffff0000u);
                    s2 += q2[j] * kv2;
                }
                lg[k] = (s2.x + s2.y + qb) * 0.35355339059327373f;   // 1/sqrt(8)
            }
            float m = lg[0];
            #pragma unroll
            for (int k = 1; k < 9; k++) m = fmaxf(m, lg[k]);
            float sum = 0.f;
            #pragma unroll
            for (int k = 0; k < 9; k++) { lg[k] = __expf(lg[k] - m); sum += lg[k]; }
            float inv = 1.f / sum;
            f32x2 ov[4];
            #pragma unroll
            for (int j = 0; j < 4; j++) ov[j] = bv2[j];
            #pragma unroll
            for (int k = 0; k < 9; k++) {
                uint4 v8 = *(const uint4*)&kv_s[(pxl4*9 + k)*KROW + 96 + h*8];
                float pw = lg[k] * inv;
                f32x2 p2; p2.x = pw; p2.y = pw;
                #pragma unroll
                for (int j = 0; j < 4; j++) {
                    unsigned uu = (&v8.x)[j];
                    f32x2 vv;
                    vv.x = __uint_as_float(uu << 16);
                    vv.y = __uint_as_float(uu & 0xffff0000u);
                    ov[j] += p2 * vv;
                }
            }
            s16x8 st = pack8(ov);
            *(s16x8*)(o_bf + (size_t)gp4*96 + h*8) = st;
        }
    }
}

// ---------------------------------------------------------------------------
// Fused tail: x = Wo@o + bo + ft;  h = gelu(Wm1@x + bm1);  out = x + Wm2@h + bm2.
// One wave per block, 16 pixels. x kept in f32 regs for the final residual
// (no xbuf round-trip); ft residual read from cat (bf16 px-major, vectorized).
// ---------------------------------------------------------------------------
__launch_bounds__(64, 4)
__global__ void tail_kernel(const bf16* __restrict__ o_bf, const bf16* __restrict__ cat,
    const bf16* __restrict__ wAo, const bf16* __restrict__ wAm1, const bf16* __restrict__ wAm2,
    const float* __restrict__ bof, const float* __restrict__ bm1f, const float* __restrict__ bm2f,
    const int* __restrict__ flag, void* __restrict__ outp)
{
    __shared__ short o_s[16*104];
    __shared__ short x_s[16*104];
    __shared__ short h_s[16*200];
    int lane = threadIdx.x;
    int n = lane & 15, kq = lane >> 4;
    int gp0 = blockIdx.x * 16;

    // stage o tile: 16 px x 96 ch = 192 uint4
    for (int i = lane; i < 192; i += 64) {
        int px = (i*8)/96, c = (i*8) - ((i*8)/96)*96;
        *(uint4*)&o_s[px*104 + c] = *(const uint4*)(o_bf + (size_t)(gp0+px)*96 + c);
    }
    __syncthreads();

    int gp = gp0 + n;
    int p = gp & (Pv-1), bb = gp >> 14;

    // --- S1: x = Wo @ o + bo + ft ---
    fx4 xacc[6];
    #pragma unroll
    for (int f = 0; f < 6; f++) xacc[f] = (fx4){0.f,0.f,0.f,0.f};
    #pragma unroll
    for (int kc = 0; kc < 3; kc++) {
        s16x8 b = *(const s16x8*)&o_s[n*104 + kc*32 + kq*8];
        #pragma unroll
        for (int f = 0; f < 6; f++) {
            s16x8 a = *(const s16x8*)(wAo + ((size_t)(kc*96 + f*16 + n))*32 + kq*8);
            xacc[f] = __builtin_amdgcn_mfma_f32_16x16x32_bf16(a, b, xacc[f], 0, 0, 0);
        }
    }
    #pragma unroll
    for (int f = 0; f < 6; f++) {
        int co0 = f*16 + kq*4;
        s16x4 ft4 = *(const s16x4*)(cat + (size_t)gp*224 + co0);
        s16x4 st;
        #pragma unroll
        for (int rg = 0; rg < 4; rg++) {
            short sv = ft4[rg];
            xacc[f][rg] += bof[co0+rg] + b2f(*(bf16*)&sv);
            bf16 bv = f2b(xacc[f][rg]);
            st[rg] = *(short*)&bv;
        }
        *(s16x4*)&x_s[n*104 + co0] = st;
    }
    __syncthreads();

    // --- S2: h = gelu(Wm1 @ x + bm1), M=192 ---
    fx4 hacc[12];
    #pragma unroll
    for (int f = 0; f < 12; f++) hacc[f] = (fx4){0.f,0.f,0.f,0.f};
    #pragma unroll
    for (int kc = 0; kc < 3; kc++) {
        s16x8 b = *(const s16x8*)&x_s[n*104 + kc*32 + kq*8];
        #pragma unroll
        for (int f = 0; f < 12; f++) {
            s16x8 a = *(const s16x8*)(wAm1 + ((size_t)(kc*192 + f*16 + n))*32 + kq*8);
            hacc[f] = __builtin_amdgcn_mfma_f32_16x16x32_bf16(a, b, hacc[f], 0, 0, 0);
        }
    }
    #pragma unroll
    for (int f = 0; f < 12; f++) {
        int co0 = f*16 + kq*4;
        s16x4 st;
        #pragma unroll
        for (int rg = 0; rg < 4; rg++) {
            float v = hacc[f][rg] + bm1f[co0+rg];
            float t2 = __expf(1.5957691216057308f*(v + 0.044715f*v*v*v));
            v = v * t2 / (t2 + 1.f);   // fast tanh-GELU
            bf16 bv = f2b(v);
            st[rg] = *(short*)&bv;
        }
        *(s16x4*)&h_s[n*200 + co0] = st;
    }
    __syncthreads();

    // --- S3: out = x + Wm2 @ h + bm2, M=96, K=192 ---
    fx4 oacc[6];
    #pragma unroll
    for (int f = 0; f < 6; f++) oacc[f] = (fx4){0.f,0.f,0.f,0.f};
    #pragma unroll
    for (int kc = 0; kc < 6; kc++) {
        s16x8 b = *(const s16x8*)&h_s[n*200 + kc*32 + kq*8];
        #pragma unroll
        for (int f = 0; f < 6; f++) {
            s16x8 a = *(const s16x8*)(wAm2 + ((size_t)(kc*96 + f*16 + n))*32 + kq*8);
            oacc[f] = __builtin_amdgcn_mfma_f32_16x16x32_bf16(a, b, oacc[f], 0, 0, 0);
        }
    }
    int isf = flag[0];
    #pragma unroll
    for (int f = 0; f < 6; f++) {
        int co0 = f*16 + kq*4;
        #pragma unroll
        for (int rg = 0; rg < 4; rg++) {
            int co = co0 + rg;
            size_t oi = ((size_t)bb*Cv + co)*Pv + p;
            float v = oacc[f][rg] + bm2f[co] + xacc[f][rg];
            if (isf) ((float*)outp)[oi] = v;
            else     ((bf16*)outp)[oi] = f2b(v);
        }
    }
}

// ---------------------------------------------------------------------------
extern "C" void kernel_launch(void* const* d_in, const int* in_sizes, int n_in,
                              void* d_out, int out_size, void* d_ws, size_t ws_size,
                              hipStream_t stream) {
    (void)in_sizes; (void)n_in; (void)out_size; (void)ws_size;

    char* w = (char*)d_ws;
    bf16*  fkvclb = (bf16*) (w + 12582912);      //  6,291,456
    float* flowf  = (float*)(w + 18874368);      //    262,144
    bf16*  wAkv   = (bf16*) (w + 19136512);      //     36,864
    bf16*  wAq    = (bf16*) (w + 19173376);      //     18,432
    bf16*  wAo    = (bf16*) (w + 19191808);      //     18,432
    bf16*  wA1    = (bf16*) (w + 19210240);      //    774,144
    bf16*  wA2    = (bf16*) (w + 19984384);      //    331,776
    bf16*  wA3    = (bf16*) (w + 20316160);      //    387,072 (224-co layout)
    bf16*  wAm1   = (bf16*) (w + 20758528);      //     36,864
    bf16*  wAm2   = (bf16*) (w + 20795392);      //     36,864
    float* biasf  = (float*)(w + 20832256);      //      8,192 (biases use 5,856)
    float* zbuf   = biasf + 1536;                //   256B zero region (OOB source)
    int*   flag   = (int*)  (w + 20840448);      //        256
    // region A (14,680,064): cat[gp][224] — live transpose/build_cat -> tail
    char*  regA   = w + 20840704;
    // region B (14,155,776): r1b (conv1->conv2) / off3 (conv3->dka)
    char*  regB   = w + 35520768;
    // region C (6,291,456): r2b (conv2->conv3) / q_bf (q_gemm->dka)
    char*  regC   = w + 49676544;
    // region D (6,291,456): o_bf (dka->tail)
    char*  regD   = w + 55968000;
    // total 62,259,456 bytes

    bf16*  cat   = (bf16*) regA;
    bf16*  r1b   = (bf16*) regB;
    bf16*  off3  = (bf16*) regB;
    bf16*  r2b   = (bf16*) regC;
    bf16*  q_bf  = (bf16*) regC;
    bf16*  o_bf  = (bf16*) regD;

    detect_dtype<<<1, 256, 0, stream>>>((const unsigned short*)d_in[0], flag, zbuf);

    // LDS-tiled transpose of feat_t -> cat[.][0..95] and feat_kv -> fkvclb
    transpose_feats<<<NPIX/64, 256, 0, stream>>>(flag, d_in[0], d_in[1], cat, fkvclb);

    prep_weights<<<1536, 256, 0, stream>>>(flag,
        d_in[2],
        d_in[3], d_in[4], d_in[5], d_in[6], d_in[7], d_in[8], d_in[9], d_in[10],
        d_in[11], d_in[12], d_in[13], d_in[14], d_in[15], d_in[16], d_in[17], d_in[18],
        d_in[19], d_in[20], d_in[21], d_in[22],
        flowf, wAq, wAo, wAkv, wA1, wA2, wA3, wAm1, wAm2, biasf);

    build_cat<<<(NPIX*16 + 255)/256, 256, 0, stream>>>(fkvclb, flowf, cat);

    // conv1: GY=4, COF=3 -> 1024 blocks (LDS 52.6KB -> 3 blocks/CU)
    conv_mfma<224, 224, 192, 3, 9, 0, 192, 4><<<1024, 256, 0, stream>>>(
        cat, wA1, biasf + 0,   biasf + 192, zbuf, flag, r1b, nullptr);
    // conv2: GY=3, COF=2 -> 768 blocks (LDS 43.4KB -> 3 blocks/CU)
    conv_mfma<192, 192,  96, 2, 9, 0,  96, 3><<<768, 256, 0, stream>>>(
        r1b, wA2, biasf + 384, biasf + 480, zbuf, flag, r2b, nullptr);
    // conv3: COF=2, GY=7 (COTOT=224, 216 real) -> 1792 blocks (LDS 43.4KB -> 3/CU)
    conv_mfma< 96,  96, 224, 2, 9, 1, 216, 7><<<1792, 256, 0, stream>>>(
        r2b, wA3, biasf + 576, nullptr,     zbuf, flag, off3, nullptr);

    // q = Wq @ feat_t + bq  (reads feat_t channels from cat, stride 224)
    conv_mfma<224,  96,  96, 2, 1, 1,  96, 3><<<768, 256, 0, stream>>>(
        cat, wAq, biasf + 792, nullptr,     zbuf, flag, q_bf, nullptr);

    // fused deformable attention (sample + kv GEMM + softmax + o)
    dka_kernel<<<(NPIX + PPB - 1)/PPB, 256, 0, stream>>>(
        flowf, fkvclb, off3, q_bf, wAkv, biasf + 888, biasf + 984, o_bf);

    // fused tail: o-projection + residual + MLP1(GELU) + MLP2 + residual -> d_out
    tail_kernel<<<NPIX/16, 64, 0, stream>>>(
        o_bf, cat, wAo, wAm1, wAm2,
        biasf + 1080, biasf + 1176, biasf + 1368, flag, d_out);
}

// Round 13
// 294.677 us; speedup vs baseline: 1.0165x; 1.0165x over previous
//
#include <hip/hip_runtime.h>
#include <hip/hip_bf16.h>
#include <math.h>

typedef __hip_bfloat16 bf16;
typedef __attribute__((ext_vector_type(8))) short s16x8;
typedef __attribute__((ext_vector_type(4))) short s16x4;
typedef __attribute__((ext_vector_type(4))) float fx4;
typedef __attribute__((ext_vector_type(2))) float f32x2;

#define Bv 2
#define Cv 96
#define Hv 128
#define Wv 128
#define Pv (Hv*Wv)          /* 16384 */
#define NPIX (Bv*Pv)        /* 32768 */
#define Gv 12
#define Kv 9
#define PPB 7               /* pixels per dka block */
#define NPT 64              /* 63 points + 1 pad    */
#define SROW 104            /* dka s_s row pitch (shorts) — 208B, 16B-aligned rows */
#define KROW 200            /* dka kv_s row pitch (shorts) — 400B, 16B-aligned rows */

__device__ __forceinline__ float b2f(bf16 x) { return __bfloat162float(x); }
__device__ __forceinline__ bf16 f2b(float x) { return __float2bfloat16(x); }

// async 16B global -> LDS (DMA, no VGPR round-trip). LDS dest is wave-uniform
// base + lane*16 (linear); per-lane GLOBAL address may be arbitrary.
__device__ __forceinline__ void gld16(const void* g, void* l) {
    __builtin_amdgcn_global_load_lds(
        (const __attribute__((address_space(1))) unsigned int*)g,
        (__attribute__((address_space(3))) unsigned int*)l, 16, 0, 0);
}

// dual-dtype input load: isf=1 -> float32, isf=0 -> bf16
__device__ __forceinline__ float ldin(const void* p, size_t i, int isf) {
    return isf ? ((const float*)p)[i] : __bfloat162float(((const bf16*)p)[i]);
}

// packed bilinear accumulate: acc[4] (8 ch as f32 pairs) += wt * bf16x8(d)
__device__ __forceinline__ void acc_pk(f32x2 acc[4], uint4 d, float wt) {
    f32x2 w2; w2.x = wt; w2.y = wt;
    #pragma unroll
    for (int q = 0; q < 4; q++) {
        unsigned u = (&d.x)[q];
        f32x2 v;
        v.x = __uint_as_float(u << 16);
        v.y = __uint_as_float(u & 0xffff0000u);
        acc[q] += w2 * v;
    }
}

__device__ __forceinline__ s16x8 pack8(const f32x2 a[4]) {
    s16x8 st;
    #pragma unroll
    for (int q = 0; q < 4; q++) {
        bf16 l = f2b(a[q].x), h = f2b(a[q].y);
        st[q*2]   = *(short*)&l;
        st[q*2+1] = *(short*)&h;
    }
    return st;
}

// ---------------------------------------------------------------------------
// dtype detection (f32 read as bf16 shows NaN/Inf bit patterns in low halves)
// + zero-fill of the zbuf region (OOB source for global_load_lds staging).
// ---------------------------------------------------------------------------
__global__ void detect_dtype(const unsigned short* __restrict__ x, int* __restrict__ flag,
                             float* __restrict__ zbuf)
{
    __shared__ int bad;
    if (threadIdx.x == 0) bad = 0;
    if (threadIdx.x < 64) zbuf[threadIdx.x] = 0.f;   // 256B zero region
    __syncthreads();
    int cnt = 0;
    for (int i = threadIdx.x; i < 32768; i += 256) {
        unsigned short u = x[i];
        if ((u & 0x7F80) == 0x7F80) cnt++;
    }
    atomicAdd(&bad, cnt);
    __syncthreads();
    if (threadIdx.x == 0) flag[0] = (bad > 0) ? 1 : 0;   // 1 = float32 inputs
}

// ---------------------------------------------------------------------------
// transpose_feats: [b][c][p] -> px-major bf16 via LDS tile.
// Phase A: coalesced read along p (lane=pixel), store LDS [px][c] (pitch 104).
// Phase B: contiguous s16x8 bursts to cat[gp][0..95] and fkvclb[gp][0..95].
// ---------------------------------------------------------------------------
__global__ void transpose_feats(const int* __restrict__ flag,
                                const void* ft, const void* fkv,
                                bf16* __restrict__ cat, bf16* __restrict__ fkvclb)
{
    __shared__ short tft[64*104];
    __shared__ short tkv[64*104];
    int tid = threadIdx.x;
    int isf = flag[0];
    int gp0 = blockIdx.x * 64;           // 64 | Pv -> whole tile in one batch b
    int bb  = gp0 >> 14;
    int p0  = gp0 & (Pv-1);

    // phase A: 96 c x 64 px; lane = px (coalesced); 24 iters per tensor
    for (int e = tid; e < 96*64; e += 256) {
        int c = e >> 6, dp = e & 63;
        size_t gi = ((size_t)bb*96 + c)*Pv + p0 + dp;
        bf16 v1 = f2b(ldin(ft,  gi, isf));
        bf16 v2 = f2b(ldin(fkv, gi, isf));
        tft[dp*104 + c] = *(short*)&v1;
        tkv[dp*104 + c] = *(short*)&v2;
    }
    __syncthreads();

    // phase B: 64 px x 12 groups; consecutive lanes cover one pixel's 192B
    for (int u = tid; u < 64*12; u += 256) {
        int g = u % 12, px = u / 12;
        s16x8 a = *(const s16x8*)&tft[px*104 + g*8];
        s16x8 b = *(const s16x8*)&tkv[px*104 + g*8];
        *(s16x8*)(cat    + (size_t)(gp0+px)*224 + g*8) = a;
        *(s16x8*)(fkvclb + (size_t)(gp0+px)*96  + g*8) = b;
    }
}

// ---------------------------------------------------------------------------
// prep_weights: build MFMA A-layout weight buffers (bf16) + flowf + biases.
// ---------------------------------------------------------------------------
__global__ void prep_weights(const int* __restrict__ flag,
    const void* flow,
    const void* cw1, const void* cb1, const void* a1,
    const void* cw2, const void* cb2, const void* a2,
    const void* cw3, const void* cb3,
    const void* wq, const void* bq, const void* wk, const void* bk,
    const void* wv, const void* bv, const void* wo, const void* bo,
    const void* wm1, const void* bm1, const void* wm2, const void* bm2,
    float* __restrict__ flowf,
    bf16* __restrict__ wAq, bf16* __restrict__ wAo, bf16* __restrict__ wAkv,
    bf16* __restrict__ wA1, bf16* __restrict__ wA2, bf16* __restrict__ wA3,
    bf16* __restrict__ wAm1, bf16* __restrict__ wAm2,
    float* __restrict__ biasf)
{
    int isf = flag[0];
    size_t i = (size_t)blockIdx.x * 256 + threadIdx.x;
    if (i < (size_t)Bv*2*Pv) flowf[i] = ldin(flow, i, isf);

    // conv1 weights: [192][194][9] -> wA1[t<9][kc<7][co<192][32]
    if (i < 9*7*192*32) {
        int q = (int)(i & 31);
        int rest = (int)(i >> 5);
        int co = rest % 192; rest /= 192;
        int kc = rest % 7;   int t = rest / 7;
        int ci = kc*32 + q;
        float v = (ci < 194) ? ldin(cw1, (size_t)co*194*9 + (size_t)ci*9 + t, isf) : 0.f;
        wA1[i] = f2b(v);
    }
    // conv2: [96][192][9] -> wA2[t<9][kc<6][co<96][32]
    if (i < 9*6*96*32) {
        int q = (int)(i & 31);
        int rest = (int)(i >> 5);
        int co = rest % 96; rest /= 96;
        int kc = rest % 6;  int t = rest / 6;
        int ci = kc*32 + q;
        wA2[i] = f2b(ldin(cw2, (size_t)co*192*9 + (size_t)ci*9 + t, isf));
    }
    // conv3: [216][96][9] -> wA3[t<9][kc<3][co<256][32], co>=216 zero
    if (i < 9*3*256*32) {
        int q = (int)(i & 31);
        int rest = (int)(i >> 5);
        int co = rest % 256; rest /= 256;
        int kc = rest % 3;   int t = rest / 3;
        int ci = kc*32 + q;
        float v = (co < 216) ? ldin(cw3, (size_t)co*96*9 + (size_t)ci*9 + t, isf) : 0.f;
        wA3[i] = f2b(v);
    }
    // mlp1: [192][96] -> wAm1[kc<3][co<192][32]
    if (i < 3*192*32) {
        int q = (int)(i & 31);
        int rest = (int)(i >> 5);
        int co = rest % 192;
        int kc = rest / 192;
        wAm1[i] = f2b(ldin(wm1, (size_t)co*96 + kc*32 + q, isf));
    }
    // mlp2: [96][192] -> wAm2[kc<6][co<96][32]
    if (i < 6*96*32) {
        int q = (int)(i & 31);
        int rest = (int)(i >> 5);
        int co = rest % 96;
        int kc = rest / 96;
        wAm2[i] = f2b(ldin(wm2, (size_t)co*192 + kc*32 + q, isf));
    }
    // wq / wo: [96][96] -> A-layout [kc<3][co<96][32]
    if (i < 3*96*32) {
        int q = (int)(i & 31);
        int rest = (int)(i >> 5);
        int co = rest % 96;
        int kc = rest / 96;
        wAq[i] = f2b(ldin(wq, (size_t)co*96 + kc*32 + q, isf));
        wAo[i] = f2b(ldin(wo, (size_t)co*96 + kc*32 + q, isf));
    }
    // wk/wv fused A-layout: wAkv[kc<3][co<192][32]; co<96 -> wk[co], co>=96 -> wv[co-96]
    if (i < 3*192*32) {
        int q = (int)(i & 31);
        int rest = (int)(i >> 5);
        int co = rest % 192;
        int kc = rest / 192;
        int ci = kc*32 + q;
        float v = (co < 96) ? ldin(wk, (size_t)co*96 + ci, isf)
                            : ldin(wv, (size_t)(co-96)*96 + ci, isf);
        wAkv[i] = f2b(v);
    }
    if (i < 192) biasf[i]       = ldin(cb1, i, isf);
    if (i < 192) biasf[192+i]   = ldin(a1, i, isf);
    if (i < 96)  biasf[384+i]   = ldin(cb2, i, isf);
    if (i < 96)  biasf[480+i]   = ldin(a2, i, isf);
    if (i < 216) biasf[576+i]   = ldin(cb3, i, isf);
    if (i < 96) {
        biasf[792+i]  = ldin(bq, i, isf);
        biasf[888+i]  = ldin(bk, i, isf);
        biasf[984+i]  = ldin(bv, i, isf);
        biasf[1080+i] = ldin(bo, i, isf);
        biasf[1368+i] = ldin(bm2, i, isf);
    }
    if (i < 192) biasf[1176+i] = ldin(bm1, i, isf);
}

// ---------------------------------------------------------------------------
// cat groups 12..27 only (feat_t groups 0..11 written by transpose_feats).
// 12..23 = flow-warped kv (packed bilinear), 24 = flow+pad, 25..27 = 0.
// ---------------------------------------------------------------------------
__global__ void build_cat(const bf16* __restrict__ fkvclb,
                          const float* __restrict__ flowf, bf16* __restrict__ cat)
{
    int idx = blockIdx.x * 256 + threadIdx.x;
    if (idx >= NPIX*16) return;
    int grp = 12 + (idx & 15);
    int gp  = idx >> 4;
    int p   = gp & (Pv-1);
    int bb  = gp >> 14;
    s16x8 st;
    if (grp < 24) {
        int g = grp - 12;
        int py = p >> 7, px = p & (Wv-1);
        float xs = (float)px + flowf[((size_t)bb*2 + 0)*Pv + p];
        float ys = (float)py + flowf[((size_t)bb*2 + 1)*Pv + p];
        float x0f = floorf(xs), y0f = floorf(ys);
        float wx = xs - x0f, wy = ys - y0f;
        int x0 = (int)x0f, y0 = (int)y0f;
        const bf16* base = fkvclb + ((size_t)bb*Pv)*96 + g*8;
        float w[4]; uint4 t4[4];
        #pragma unroll
        for (int t = 0; t < 4; t++) {
            int xi = x0 + (t & 1), yi = y0 + (t >> 1);
            float wt = ((t & 1) ? wx : 1.f - wx) * ((t >> 1) ? wy : 1.f - wy);
            bool vld = (xi >= 0) & (xi < Wv) & (yi >= 0) & (yi < Hv);
            int xc = min(max(xi, 0), Wv-1), yc = min(max(yi, 0), Hv-1);
            w[t] = vld ? wt : 0.f;
            t4[t] = *(const uint4*)(base + (size_t)(yc*Wv + xc)*96);
        }
        f32x2 acc[4];
        #pragma unroll
        for (int q = 0; q < 4; q++) { acc[q].x = 0.f; acc[q].y = 0.f; }
        #pragma unroll
        for (int t = 0; t < 4; t++) acc_pk(acc, t4[t], w[t]);
        st = pack8(acc);
    } else if (grp == 24) {
        float fx = flowf[((size_t)bb*2 + 0)*Pv + p];
        float fy = flowf[((size_t)bb*2 + 1)*Pv + p];
        bf16 b0 = f2b(fx), b1 = f2b(fy);
        st[0] = *(short*)&b0; st[1] = *(short*)&b1;
        #pragma unroll
        for (int j = 2; j < 8; j++) st[j] = 0;
    } else {
        #pragma unroll
        for (int j = 0; j < 8; j++) st[j] = 0;
    }
    *(s16x8*)(cat + (size_t)gp*224 + grp*8) = st;
}

// ---------------------------------------------------------------------------
// MFMA implicit-GEMM conv/1x1. 1-D grid of 128*GY*Bv blocks, XCD-aware decode.
// Staging via __builtin_amdgcn_global_load_lds (16B DMA, no VGPR round-trip,
// no spill possible). LDS is LINEAR in chunk index; bank-conflict swizzle is
// applied on the SOURCE address (rule #21): LDS chunk (row,kqs) holds global
// chunk (row, kqs ^ ((row>>1)&3)); readers XOR the same key.
// OOB border pixels: source redirected to a 256B zero buffer (zbuf).
// MODE 0: PReLU -> bf16 px-major    MODE 1: plain -> bf16 px-major (guard co<216)
// ---------------------------------------------------------------------------
template<int CSTR, int CIN_PAD, int COTOT, int COF, int TAPS, int MODE, int OCS, int GY>
__launch_bounds__(256)
__global__ void conv_mfma(const bf16* __restrict__ in, const bf16* __restrict__ wA,
                          const float* __restrict__ bias, const float* __restrict__ alpha,
                          const float* __restrict__ zbuf, const int* __restrict__ flag,
                          void* __restrict__ outp, void* __restrict__ out2)
{
    constexpr int NC = CIN_PAD / 32;
    constexpr int LDS_PX = (TAPS == 9) ? 3*130 : 128;
    constexpr int NITEMS = LDS_PX * 4;              // input 16B chunks per kc
    constexpr int NSTG = (NITEMS + 255) / 256;
    constexpr int NWCH  = TAPS * COF * 64;          // weight 16B chunks per kc
    constexpr int NWSTG = (NWCH + 255) / 256;
    __shared__ __align__(16) short sbuf[LDS_PX * 32];        // linear chunks
    __shared__ __align__(16) short wlds[TAPS * COF * 512];   // linear chunks

    int tid = threadIdx.x;
    int wave = tid >> 6, lane = tid & 63;
    int n = lane & 15, kq = lane >> 4;

    int bid = blockIdx.x;
    int xcd = bid & 7, idx = bid >> 3;
    int y   = xcd * 16 + (idx & 15);
    int cob = ((idx >> 4) % GY) * (COF*16);
    int bb  = idx / (16*GY);

    // async input staging: chunk i -> sbuf linear; source pre-swizzled
    auto stage_in = [&](int kc) {
        #pragma unroll
        for (int s = 0; s < NSTG; s++) {
            int i = s*256 + tid;
            if (i < NITEMS) {
                int pxr = i >> 2;
                int kqs = i & 3;
                int part = kqs ^ ((pxr >> 1) & 3);
                const bf16* ap;
                if (TAPS == 9) {
                    int r = pxr / 130; int px = pxr - r*130;
                    int yy = y + r - 1, xx = px - 1;
                    bool inb = (yy >= 0) & (yy < Hv) & (xx >= 0) & (xx < Wv);
                    ap = inb ? (in + ((size_t)(bb*Pv + yy*Wv + xx)*CSTR + kc*32 + part*8))
                             : (const bf16*)zbuf;
                } else {
                    ap = in + ((size_t)(bb*Pv + y*Wv + pxr)*CSTR + kc*32 + part*8);
                }
                gld16(ap, &sbuf[(size_t)(i & ~63) * 8]);   // wave-uniform base
            }
        }
    };
    // async weight staging: chunk i -> wlds linear; source pre-swizzled
    auto stage_w = [&](int kc) {
        #pragma unroll
        for (int s = 0; s < NWSTG; s++) {
            int i = s*256 + tid;
            if (i < NWCH) {
                int t = i / (COF*64);
                int rem = i - t*(COF*64);
                int row = rem >> 2, kqs = rem & 3;
                int part = kqs ^ ((row >> 1) & 3);
                const bf16* ap = wA + ((size_t)((t*NC + kc)*COTOT + cob + row))*32 + part*8;
                gld16(ap, &wlds[(size_t)(i & ~63) * 8]);   // wave-uniform base
            }
        }
    };

    fx4 acc[COF][2];
    #pragma unroll
    for (int f = 0; f < COF; f++)
        #pragma unroll
        for (int j = 0; j < 2; j++)
            acc[f][j] = (fx4){0.f, 0.f, 0.f, 0.f};

    int kqsw = kq ^ ((n >> 1) & 3);                  // weight-read swizzled chunk

    for (int kc = 0; kc < NC; kc++) {
        stage_in(kc); stage_w(kc);
        __syncthreads();                             // drains vmcnt (LDS ready)
        #pragma unroll
        for (int t = 0; t < TAPS; t++) {
            s16x8 wf[COF];
            #pragma unroll
            for (int f = 0; f < COF; f++)
                wf[f] = *(const s16x8*)&wlds[(size_t)(((t*COF + f)*16 + n)*4 + kqsw) * 8];
            #pragma unroll
            for (int j = 0; j < 2; j++) {
                int pxs;
                if (TAPS == 9) {
                    int r = t / 3, dx = t % 3;
                    pxs = r*130 + wave*32 + j*16 + n + dx;
                } else {
                    pxs = wave*32 + j*16 + n;
                }
                int kqi = kq ^ ((pxs >> 1) & 3);
                s16x8 bfr = *(const s16x8*)&sbuf[(size_t)(pxs*4 + kqi) * 8];
                #pragma unroll
                for (int f = 0; f < COF; f++)
                    acc[f][j] = __builtin_amdgcn_mfma_f32_16x16x32_bf16(wf[f], bfr, acc[f][j], 0, 0, 0);
            }
        }
        __syncthreads();                             // WAR before next staging
    }

    // epilogue: D col=lane&15 (pixel), row=(lane>>4)*4+reg (co)
    int pxbase = wave*32;
    #pragma unroll
    for (int f = 0; f < COF; f++) {
        int co0 = cob + f*16 + kq*4;
        if (MODE == 1 && co0 >= 216) continue;
        #pragma unroll
        for (int j = 0; j < 2; j++) {
            int px = pxbase + j*16 + n;
            size_t gp = (size_t)bb*Pv + (size_t)y*Wv + px;
            fx4 fr = acc[f][j];
            s16x4 st;
            #pragma unroll
            for (int rg = 0; rg < 4; rg++) {
                float v = fr[rg] + bias[co0 + rg];
                if (MODE == 0) { float a = alpha[co0 + rg]; v = (v >= 0.f) ? v : a*v; }
                bf16 bvv = f2b(v);
                st[rg] = *(short*)&bvv;
            }
            *(s16x4*)((bf16*)outp + gp*OCS + co0) = st;
        }
    }
    (void)flag; (void)out2;
}

// ---------------------------------------------------------------------------
// Fused deformable attention: sample -> kv MFMA GEMM -> softmax -> o.
// Block 256 = 4 waves, 7 pixels = 63 points (+1 pad) per block.
// Phase-1 mapping: tid -> (pt = tid>>2, g = (tid&3)*3 + r); r-invariant pixel
// decode; 2-stage gather pipeline. kv_s ALIASES s_s.
// Phase 4: one thread per (pixel, head) — head dim 8 is contiguous in kv_s
// rows and q_bf, so q/k/v are single 16B vectors. No shfl, no scalar reads.
// ---------------------------------------------------------------------------
__launch_bounds__(256, 4)
__global__ void dka_kernel(const float* __restrict__ flowf, const bf16* __restrict__ fkvclb,
    const bf16* __restrict__ off3, const bf16* __restrict__ q_bf,
    const bf16* __restrict__ wAkv, const float* __restrict__ bkf, const float* __restrict__ bvf,
    bf16* __restrict__ o_bf)
{
    __shared__ short smem[NPT*KROW];    // union: s_s [pt][SROW] then kv_s [pt][KROW]
    short* s_s  = smem;
    short* kv_s = smem;

    int tid = threadIdx.x;
    int pb0 = blockIdx.x * PPB;

    // --- phase 1 prologue (r-invariant) ---
    int pt  = tid >> 2;                 // point 0..63
    int gb  = (tid & 3) * 3;            // group base {0,3,6,9}
    int pxl = pt / 9;
    int tap = pt - pxl*9;
    int gp0 = pb0 + pxl;
    bool act = (pt < 63) && (gp0 < NPIX);
    int gp = act ? gp0 : (NPIX-1);
    int bb = gp >> 14, p = gp & (Pv-1);
    int py = p >> 7, px = p & (Wv-1);
    float fx = flowf[((size_t)bb*2 + 0)*Pv + p];
    float fy = flowf[((size_t)bb*2 + 1)*Pv + p];
    float sbx = (float)(px + (tap % 3) - 1) + fx;
    float sby = (float)(py + (tap / 3) - 1) + fy;
    const bf16* kvbase = fkvclb + ((size_t)bb*Pv)*96;
    unsigned owv[3];
    #pragma unroll
    for (int r = 0; r < 3; r++)
        owv[r] = *(const unsigned*)(off3 + (size_t)gp*216 + ((gb + r)*9 + tap)*2);  // (dy,dx)

    float wst[2][4]; uint4 tst[2][4];
    auto stage = [&](int r, int s) {
        unsigned ow = owv[r];
        unsigned short lo16 = (unsigned short)(ow & 0xFFFFu);
        unsigned short hi16 = (unsigned short)(ow >> 16);
        float sy = sby + b2f(*(bf16*)&lo16);
        float sx = sbx + b2f(*(bf16*)&hi16);
        float x0f = floorf(sx), y0f = floorf(sy);
        float wx1 = sx - x0f, wy1 = sy - y0f;
        float wx0 = 1.f - wx1, wy0 = 1.f - wy1;
        int ix0 = (int)x0f, iy0 = (int)y0f;
        bool vx0 = (unsigned)ix0     < (unsigned)Wv;
        bool vx1 = (unsigned)(ix0+1) < (unsigned)Wv;
        bool vy0 = (unsigned)iy0     < (unsigned)Hv;
        bool vy1 = (unsigned)(iy0+1) < (unsigned)Hv;
        float mx0 = (act && vx0) ? wx0 : 0.f;
        float mx1 = (act && vx1) ? wx1 : 0.f;
        float my0 = vy0 ? wy0 : 0.f;
        float my1 = vy1 ? wy1 : 0.f;
        wst[s][0] = mx0*my0; wst[s][1] = mx1*my0;
        wst[s][2] = mx0*my1; wst[s][3] = mx1*my1;
        int xc0 = min(max(ix0,   0), Wv-1), xc1 = min(max(ix0+1, 0), Wv-1);
        int yc0 = min(max(iy0,   0), Hv-1), yc1 = min(max(iy0+1, 0), Hv-1);
        const bf16* bg = kvbase + (gb + r)*8;
        int r0 = yc0*(Wv*96), r1 = yc1*(Wv*96);
        int c0 = xc0*96,      c1 = xc1*96;
        tst[s][0] = *(const uint4*)(bg + r0 + c0);
        tst[s][1] = *(const uint4*)(bg + r0 + c1);
        tst[s][2] = *(const uint4*)(bg + r1 + c0);
        tst[s][3] = *(const uint4*)(bg + r1 + c1);
    };
    auto emit = [&](int r, int s) {
        f32x2 acc[4];
        #pragma unroll
        for (int q = 0; q < 4; q++) { acc[q].x = 0.f; acc[q].y = 0.f; }
        #pragma unroll
        for (int t = 0; t < 4; t++) acc_pk(acc, tst[s][t], wst[s][t]);
        s16x8 st = pack8(acc);
        *(s16x8*)&s_s[pt*SROW + (gb + r)*8] = st;
    };

    stage(0, 0);
    asm volatile("" ::: "memory");   // force r=0 gathers issued
    stage(1, 1);
    asm volatile("" ::: "memory");   // force r=1 gathers issued before consuming r=0
    emit(0, 0);
    stage(2, 0);
    asm volatile("" ::: "memory");
    emit(1, 1);
    emit(2, 0);
    __syncthreads();

    // --- phase 2: kv = wAkv @ s  (M=192 split over waves, N=64, K=96) ---
    {
        int wave = tid >> 6, lane = tid & 63;
        int n = lane & 15, kq = lane >> 4;
        fx4 acc[3][4];
        #pragma unroll
        for (int mi = 0; mi < 3; mi++)
            #pragma unroll
            for (int nf = 0; nf < 4; nf++)
                acc[mi][nf] = (fx4){0.f, 0.f, 0.f, 0.f};
        #pragma unroll
        for (int kc = 0; kc < 3; kc++) {
            s16x8 b[4];
            #pragma unroll
            for (int nf = 0; nf < 4; nf++)
                b[nf] = *(const s16x8*)&s_s[(nf*16 + n)*SROW + kc*32 + kq*8];
            #pragma unroll
            for (int mi = 0; mi < 3; mi++) {
                s16x8 a = *(const s16x8*)(wAkv + ((size_t)(kc*192 + (wave*3 + mi)*16 + n))*32 + kq*8);
                #pragma unroll
                for (int nf = 0; nf < 4; nf++)
                    acc[mi][nf] = __builtin_amdgcn_mfma_f32_16x16x32_bf16(a, b[nf], acc[mi][nf], 0, 0, 0);
            }
        }
        __syncthreads();   // all s_s reads drained; kv_s may now overwrite the region
        // phase 3: stage kv to LDS. D: col=point(lane&15), row=co((lane>>4)*4+rg)
        #pragma unroll
        for (int mi = 0; mi < 3; mi++)
            #pragma unroll
            for (int nf = 0; nf < 4; nf++) {
                s16x4 st;
                #pragma unroll
                for (int rg = 0; rg < 4; rg++) {
                    bf16 bv = f2b(acc[mi][nf][rg]);
                    st[rg] = *(short*)&bv;
                }
                *(s16x4*)&kv_s[(size_t)(nf*16 + n)*KROW + (wave*3 + mi)*16 + kq*4] = st;
            }
    }
    __syncthreads();

    // --- phase 4: per-(pixel,head) lane-local softmax (no shfl, no u16 reads).
    // bk hoisted: qb = sum_d q_d*bk_d; bv hoisted: sum_k p_k = 1.
    {
        int u = tid;                       // unit = pixel*12 + head, 84 units
        int pxl4 = u / 12, h = u - pxl4*12;
        int gp4 = pb0 + pxl4;
        if (u < PPB*12 && gp4 < NPIX) {
            uint4 q8 = *(const uint4*)(q_bf + (size_t)gp4*96 + h*8);
            f32x2 q2[4];
            #pragma unroll
            for (int j = 0; j < 4; j++) {
                unsigned uu = (&q8.x)[j];
                q2[j].x = __uint_as_float(uu << 16);
                q2[j].y = __uint_as_float(uu & 0xffff0000u);
            }
            const f32x2* bk2 = (const f32x2*)(bkf + h*8);
            const f32x2* bv2 = (const f32x2*)(bvf + h*8);
            f32x2 qb2; qb2.x = 0.f; qb2.y = 0.f;
            #pragma unroll
            for (int j = 0; j < 4; j++) qb2 += q2[j] * bk2[j];
            float qb = qb2.x + qb2.y;
            float lg[9];
            #pragma unroll
            for (int k = 0; k < 9; k++) {
                uint4 k8 = *(const uint4*)&kv_s[(pxl4*9 + k)*KROW + h*8];
                f32x2 s2; s2.x = 0.f; s2.y = 0.f;
                #pragma unroll
                for (int j = 0; j < 4; j++) {
                    unsigned uu = (&k8.x)[j];
                    f32x2 kv2;
                    kv2.x = __uint_as_float(uu << 16);
                    kv2.y = __uint_as_float(uu & 0xffff0000u);
                    s2 += q2[j] * kv2;
                }
                lg[k] = (s2.x + s2.y + qb) * 0.35355339059327373f;   // 1/sqrt(8)
            }
            float m = lg[0];
            #pragma unroll
            for (int k = 1; k < 9; k++) m = fmaxf(m, lg[k]);
            float sum = 0.f;
            #pragma unroll
            for (int k = 0; k < 9; k++) { lg[k] = __expf(lg[k] - m); sum += lg[k]; }
            float inv = 1.f / sum;
            f32x2 ov[4];
            #pragma unroll
            for (int j = 0; j < 4; j++) ov[j] = bv2[j];
            #pragma unroll
            for (int k = 0; k < 9; k++) {
                uint4 v8 = *(const uint4*)&kv_s[(pxl4*9 + k)*KROW + 96 + h*8];
                float pw = lg[k] * inv;
                f32x2 p2; p2.x = pw; p2.y = pw;
                #pragma unroll
                for (int j = 0; j < 4; j++) {
                    unsigned uu = (&v8.x)[j];
                    f32x2 vv;
                    vv.x = __uint_as_float(uu << 16);
                    vv.y = __uint_as_float(uu & 0xffff0000u);
                    ov[j] += p2 * vv;
                }
            }
            s16x8 st = pack8(ov);
            *(s16x8*)(o_bf + (size_t)gp4*96 + h*8) = st;
        }
    }
}

// ---------------------------------------------------------------------------
// Fused tail: x = Wo@o + bo + ft;  h = gelu(Wm1@x + bm1);  out = x + Wm2@h + bm2.
// One wave per block, 16 pixels. x kept in f32 regs for the final residual
// (no xbuf round-trip); ft residual read from cat (bf16 px-major, vectorized).
// ---------------------------------------------------------------------------
__launch_bounds__(64, 4)
__global__ void tail_kernel(const bf16* __restrict__ o_bf, const bf16* __restrict__ cat,
    const bf16* __restrict__ wAo, const bf16* __restrict__ wAm1, const bf16* __restrict__ wAm2,
    const float* __restrict__ bof, const float* __restrict__ bm1f, const float* __restrict__ bm2f,
    const int* __restrict__ flag, void* __restrict__ outp)
{
    __shared__ short o_s[16*104];
    __shared__ short x_s[16*104];
    __shared__ short h_s[16*200];
    int lane = threadIdx.x;
    int n = lane & 15, kq = lane >> 4;
    int gp0 = blockIdx.x * 16;

    // stage o tile: 16 px x 96 ch = 192 uint4
    for (int i = lane; i < 192; i += 64) {
        int px = (i*8)/96, c = (i*8) - ((i*8)/96)*96;
        *(uint4*)&o_s[px*104 + c] = *(const uint4*)(o_bf + (size_t)(gp0+px)*96 + c);
    }
    __syncthreads();

    int gp = gp0 + n;
    int p = gp & (Pv-1), bb = gp >> 14;

    // --- S1: x = Wo @ o + bo + ft ---
    fx4 xacc[6];
    #pragma unroll
    for (int f = 0; f < 6; f++) xacc[f] = (fx4){0.f,0.f,0.f,0.f};
    #pragma unroll
    for (int kc = 0; kc < 3; kc++) {
        s16x8 b = *(const s16x8*)&o_s[n*104 + kc*32 + kq*8];
        #pragma unroll
        for (int f = 0; f < 6; f++) {
            s16x8 a = *(const s16x8*)(wAo + ((size_t)(kc*96 + f*16 + n))*32 + kq*8);
            xacc[f] = __builtin_amdgcn_mfma_f32_16x16x32_bf16(a, b, xacc[f], 0, 0, 0);
        }
    }
    #pragma unroll
    for (int f = 0; f < 6; f++) {
        int co0 = f*16 + kq*4;
        s16x4 ft4 = *(const s16x4*)(cat + (size_t)gp*224 + co0);
        s16x4 st;
        #pragma unroll
        for (int rg = 0; rg < 4; rg++) {
            short sv = ft4[rg];
            xacc[f][rg] += bof[co0+rg] + b2f(*(bf16*)&sv);
            bf16 bv = f2b(xacc[f][rg]);
            st[rg] = *(short*)&bv;
        }
        *(s16x4*)&x_s[n*104 + co0] = st;
    }
    __syncthreads();

    // --- S2: h = gelu(Wm1 @ x + bm1), M=192 ---
    fx4 hacc[12];
    #pragma unroll
    for (int f = 0; f < 12; f++) hacc[f] = (fx4){0.f,0.f,0.f,0.f};
    #pragma unroll
    for (int kc = 0; kc < 3; kc++) {
        s16x8 b = *(const s16x8*)&x_s[n*104 + kc*32 + kq*8];
        #pragma unroll
        for (int f = 0; f < 12; f++) {
            s16x8 a = *(const s16x8*)(wAm1 + ((size_t)(kc*192 + f*16 + n))*32 + kq*8);
            hacc[f] = __builtin_amdgcn_mfma_f32_16x16x32_bf16(a, b, hacc[f], 0, 0, 0);
        }
    }
    #pragma unroll
    for (int f = 0; f < 12; f++) {
        int co0 = f*16 + kq*4;
        s16x4 st;
        #pragma unroll
        for (int rg = 0; rg < 4; rg++) {
            float v = hacc[f][rg] + bm1f[co0+rg];
            float t2 = __expf(1.5957691216057308f*(v + 0.044715f*v*v*v));
            v = v * t2 / (t2 + 1.f);   // fast tanh-GELU
            bf16 bv = f2b(v);
            st[rg] = *(short*)&bv;
        }
        *(s16x4*)&h_s[n*200 + co0] = st;
    }
    __syncthreads();

    // --- S3: out = x + Wm2 @ h + bm2, M=96, K=192 ---
    fx4 oacc[6];
    #pragma unroll
    for (int f = 0; f < 6; f++) oacc[f] = (fx4){0.f,0.f,0.f,0.f};
    #pragma unroll
    for (int kc = 0; kc < 6; kc++) {
        s16x8 b = *(const s16x8*)&h_s[n*200 + kc*32 + kq*8];
        #pragma unroll
        for (int f = 0; f < 6; f++) {
            s16x8 a = *(const s16x8*)(wAm2 + ((size_t)(kc*96 + f*16 + n))*32 + kq*8);
            oacc[f] = __builtin_amdgcn_mfma_f32_16x16x32_bf16(a, b, oacc[f], 0, 0, 0);
        }
    }
    int isf = flag[0];
    #pragma unroll
    for (int f = 0; f < 6; f++) {
        int co0 = f*16 + kq*4;
        #pragma unroll
        for (int rg = 0; rg < 4; rg++) {
            int co = co0 + rg;
            size_t oi = ((size_t)bb*Cv + co)*Pv + p;
            float v = oacc[f][rg] + bm2f[co] + xacc[f][rg];
            if (isf) ((float*)outp)[oi] = v;
            else     ((bf16*)outp)[oi] = f2b(v);
        }
    }
}

// ---------------------------------------------------------------------------
extern "C" void kernel_launch(void* const* d_in, const int* in_sizes, int n_in,
                              void* d_out, int out_size, void* d_ws, size_t ws_size,
                              hipStream_t stream) {
    (void)in_sizes; (void)n_in; (void)out_size; (void)ws_size;

    char* w = (char*)d_ws;
    bf16*  fkvclb = (bf16*) (w + 12582912);      //  6,291,456
    float* flowf  = (float*)(w + 18874368);      //    262,144
    bf16*  wAkv   = (bf16*) (w + 19136512);      //     36,864
    bf16*  wAq    = (bf16*) (w + 19173376);      //     18,432
    bf16*  wAo    = (bf16*) (w + 19191808);      //     18,432
    bf16*  wA1    = (bf16*) (w + 19210240);      //    774,144
    bf16*  wA2    = (bf16*) (w + 19984384);      //    331,776
    bf16*  wA3    = (bf16*) (w + 20316160);      //    442,368 (256-co layout)
    bf16*  wAm1   = (bf16*) (w + 20758528);      //     36,864
    bf16*  wAm2   = (bf16*) (w + 20795392);      //     36,864
    float* biasf  = (float*)(w + 20832256);      //      8,192 (biases use 5,856)
    float* zbuf   = biasf + 1536;                //   256B zero region (OOB source)
    int*   flag   = (int*)  (w + 20840448);      //        256
    // region A (14,680,064): cat[gp][224] — live transpose/build_cat -> tail
    char*  regA   = w + 20840704;
    // region B (14,155,776): r1b (conv1->conv2) / off3 (conv3->dka)
    char*  regB   = w + 35520768;
    // region C (6,291,456): r2b (conv2->conv3) / q_bf (q_gemm->dka)
    char*  regC   = w + 49676544;
    // region D (6,291,456): o_bf (dka->tail)
    char*  regD   = w + 55968000;
    // total 62,259,456 bytes

    bf16*  cat   = (bf16*) regA;
    bf16*  r1b   = (bf16*) regB;
    bf16*  off3  = (bf16*) regB;
    bf16*  r2b   = (bf16*) regC;
    bf16*  q_bf  = (bf16*) regC;
    bf16*  o_bf  = (bf16*) regD;

    detect_dtype<<<1, 256, 0, stream>>>((const unsigned short*)d_in[0], flag, zbuf);

    // LDS-tiled transpose of feat_t -> cat[.][0..95] and feat_kv -> fkvclb
    transpose_feats<<<NPIX/64, 256, 0, stream>>>(flag, d_in[0], d_in[1], cat, fkvclb);

    prep_weights<<<1536, 256, 0, stream>>>(flag,
        d_in[2],
        d_in[3], d_in[4], d_in[5], d_in[6], d_in[7], d_in[8], d_in[9], d_in[10],
        d_in[11], d_in[12], d_in[13], d_in[14], d_in[15], d_in[16], d_in[17], d_in[18],
        d_in[19], d_in[20], d_in[21], d_in[22],
        flowf, wAq, wAo, wAkv, wA1, wA2, wA3, wAm1, wAm2, biasf);

    build_cat<<<(NPIX*16 + 255)/256, 256, 0, stream>>>(fkvclb, flowf, cat);

    // conv1: GY=4, COF=3 -> 1024 blocks (LDS 52.6KB -> 3 blocks/CU)
    conv_mfma<224, 224, 192, 3, 9, 0, 192, 4><<<1024, 256, 0, stream>>>(
        cat, wA1, biasf + 0,   biasf + 192, zbuf, flag, r1b, nullptr);
    // conv2: GY=3, COF=2 -> 768 blocks (LDS 43.4KB -> 3 blocks/CU)
    conv_mfma<192, 192,  96, 2, 9, 0,  96, 3><<<768, 256, 0, stream>>>(
        r1b, wA2, biasf + 384, biasf + 480, zbuf, flag, r2b, nullptr);
    // conv3: GY=4, COF=4 (COTOT=256 padded) -> 1024 blocks (LDS 61.8KB -> 2/CU)
    conv_mfma< 96,  96, 256, 4, 9, 1, 216, 4><<<1024, 256, 0, stream>>>(
        r2b, wA3, biasf + 576, nullptr,     zbuf, flag, off3, nullptr);

    // q = Wq @ feat_t + bq  (reads feat_t channels from cat, stride 224)
    conv_mfma<224,  96,  96, 2, 1, 1,  96, 3><<<768, 256, 0, stream>>>(
        cat, wAq, biasf + 792, nullptr,     zbuf, flag, q_bf, nullptr);

    // fused deformable attention (sample + kv GEMM + softmax + o)
    dka_kernel<<<(NPIX + PPB - 1)/PPB, 256, 0, stream>>>(
        flowf, fkvclb, off3, q_bf, wAkv, biasf + 888, biasf + 984, o_bf);

    // fused tail: o-projection + residual + MLP1(GELU) + MLP2 + residual -> d_out
    tail_kernel<<<NPIX/16, 64, 0, stream>>>(
        o_bf, cat, wAo, wAm1, wAm2,
        biasf + 1080, biasf + 1176, biasf + 1368, flag, d_out);
}